// Round 7
// baseline (338.862 us; speedup 1.0000x reference)
//
#include <hip/hip_runtime.h>
#include <math.h>

#define TWO_N 8192
#define NR 4096
#define D 256
#define BM 128
#define BN 128
#define BK 64
#define NKT 4             // K-tiles: 4 * 64 = 256 = D
#define PMW (TWO_N / 64)  // u64 mask words per row

typedef __attribute__((ext_vector_type(8))) short bf16x8;
typedef __attribute__((ext_vector_type(4))) float f32x4;

#define AS1V const __attribute__((address_space(1))) void
#define AS3V __attribute__((address_space(3))) void
#define WAITVM(n) asm volatile("s_waitcnt vmcnt(" #n ")" ::: "memory")

__device__ inline unsigned short f2bf(float x) {
  unsigned u = __builtin_bit_cast(unsigned, x);
  u += 0x7fffu + ((u >> 16) & 1u);  // RNE
  return (unsigned short)(u >> 16);
}

// One-time f32 -> bf16 conversion of all embeddings (8192x256) into ws.
__global__ void cvt_kernel(const float* __restrict__ emb, unsigned short* __restrict__ ebf) {
  const size_t i = ((size_t)blockIdx.x * 256 + threadIdx.x) * 8;
  const float4 a = *reinterpret_cast<const float4*>(emb + i);
  const float4 b = *reinterpret_cast<const float4*>(emb + i + 4);
  union { unsigned short s[8]; bf16x8 v; } o;
  o.s[0] = f2bf(a.x); o.s[1] = f2bf(a.y); o.s[2] = f2bf(a.z); o.s[3] = f2bf(a.w);
  o.s[4] = f2bf(b.x); o.s[5] = f2bf(b.y); o.s[6] = f2bf(b.z); o.s[7] = f2bf(b.w);
  *reinterpret_cast<bf16x8*>(ebf + i) = o.v;
}

// Pack neg_mask bytes (0/1) into bits: pm[row*128 + w] bit j = negm[row][w*64+j].
__global__ void repack_kernel(const unsigned char* __restrict__ negm,
                              unsigned long long* __restrict__ pm) {
  const int t = blockIdx.x * 256 + threadIdx.x;  // word index
  const uint4* p = reinterpret_cast<const uint4*>(negm + (size_t)t * 64);
  unsigned long long w = 0;
#pragma unroll
  for (int q = 0; q < 4; ++q) {
    const uint4 v = p[q];
    unsigned b = 0;
    b |= (v.x & 1u) | ((v.x >> 7) & 2u) | ((v.x >> 14) & 4u) | ((v.x >> 21) & 8u);
    b |= ((v.y & 1u) | ((v.y >> 7) & 2u) | ((v.y >> 14) & 4u) | ((v.y >> 21) & 8u)) << 4;
    b |= ((v.z & 1u) | ((v.z >> 7) & 2u) | ((v.z >> 14) & 4u) | ((v.z >> 21) & 8u)) << 8;
    b |= ((v.w & 1u) | ((v.w >> 7) & 2u) | ((v.w >> 14) & 4u) | ((v.w >> 21) & 8u)) << 12;
    w |= (unsigned long long)b << (q * 16);
  }
  pm[t] = w;
}

// ap[i] = dot(emb[i], emb[i+NR]) (f32); also zero rowsum[i]. One wave/row.
__global__ void ap_zero_kernel(const float* __restrict__ emb, float* __restrict__ ap,
                               double* __restrict__ rowsum) {
  const int lane = threadIdx.x & 63;
  const int wid = threadIdx.x >> 6;
  const int i = blockIdx.x * 4 + wid;
  const float4 a = *reinterpret_cast<const float4*>(emb + (size_t)i * D + lane * 4);
  const float4 b = *reinterpret_cast<const float4*>(emb + (size_t)(i + NR) * D + lane * 4);
  float s = a.x * b.x + a.y * b.y + a.z * b.z + a.w * b.w;
#pragma unroll
  for (int off = 32; off >= 1; off >>= 1) s += __shfl_xor(s, off, 64);
  if (lane == 0) { ap[i] = s; rowsum[i] = 0.0; }
}

// Fused bf16-MFMA GEMM + bitmasked sum of e^(s-ap) in f64.
// Whole K resident in LDS (4 A-tiles + 4 B-tiles = 128 KB, 1 block/CU):
// all 32 global_load_lds issued up front; per K-tile counted vmcnt + raw
// s_barrier (T4) so later tiles' loads stay in flight under compute.
// T2 XOR-swizzle both-sides (rule 21): source col chunk (l&7)^(l>>3) on
// stage, chunk c^(row&7) on ds_read -> bank-uniform reads.
__global__ __launch_bounds__(256) void fused_mfma(
    const unsigned short* __restrict__ ebf, const unsigned long long* __restrict__ pm,
    const float* __restrict__ ap, double* __restrict__ rowsum) {
  __shared__ unsigned short As[NKT][BM * BK];
  __shared__ unsigned short Bs[NKT][BN * BK];
  const int t = threadIdx.x;
  const int lane = t & 63;
  const int wid = t >> 6;
  const int wr = wid >> 1;
  const int wc = wid & 1;
  // XCD-aware bijective swizzle: grid 2048 = 8 * 256.
  const int sw = (blockIdx.x & 7) * 256 + (blockIdx.x >> 3);
  const int bi = sw >> 6;  // 0..31 row tile
  const int bj = sw & 63;  // 0..63 col tile

  f32x4 acc[4][4] = {};

  const int srow = lane >> 3;                        // 0..7
  const int scol = ((lane & 7) ^ (lane >> 3)) * 8;   // inverse-swizzled source chunk

  // Issue ALL staging loads: 8 per K-tile per wave, tiles in order (vmcnt counts on this).
#pragma unroll
  for (int kt = 0; kt < NKT; ++kt) {
    const int k0 = kt * BK;
#pragma unroll
    for (int q = 0; q < 4; ++q) {
      const int rbase = wid * 32 + q * 8;  // wave-uniform
      const unsigned short* gA = ebf + (size_t)(bi * BM + rbase + srow) * D + k0 + scol;
      const unsigned short* gB = ebf + (size_t)(bj * BN + rbase + srow) * D + k0 + scol;
      __builtin_amdgcn_global_load_lds((AS1V*)gA, (AS3V*)(As[kt] + rbase * BK), 16, 0, 0);
      __builtin_amdgcn_global_load_lds((AS1V*)gB, (AS3V*)(Bs[kt] + rbase * BK), 16, 0, 0);
    }
  }

  const int frow = lane & 15;   // fragment row within 16
  const int fk = lane >> 4;     // k-group 0..3
  auto compute_kt = [&](int kt) {
#pragma unroll
    for (int kk = 0; kk < 2; ++kk) {
      bf16x8 af[4], bfr[4];
      const int cswz = ((kk * 4 + fk) ^ (lane & 7)) * 8;  // swizzled 16B chunk offset (shorts)
#pragma unroll
      for (int m = 0; m < 4; ++m)
        af[m] = *reinterpret_cast<const bf16x8*>(&As[kt][(wr * 64 + m * 16 + frow) * BK + cswz]);
#pragma unroll
      for (int n = 0; n < 4; ++n)
        bfr[n] = *reinterpret_cast<const bf16x8*>(&Bs[kt][(wc * 64 + n * 16 + frow) * BK + cswz]);
#pragma unroll
      for (int m = 0; m < 4; ++m)
#pragma unroll
        for (int n = 0; n < 4; ++n)
          acc[m][n] = __builtin_amdgcn_mfma_f32_16x16x32_bf16(af[m], bfr[n], acc[m][n], 0, 0, 0);
    }
  };

  // Per K-tile: wait only that tile's loads (8 per wave), barrier for cross-wave
  // visibility, fence the scheduler, compute. Tiles kt+1.. remain in flight.
  WAITVM(24); __builtin_amdgcn_s_barrier(); __builtin_amdgcn_sched_barrier(0);
  compute_kt(0);
  WAITVM(16); __builtin_amdgcn_s_barrier(); __builtin_amdgcn_sched_barrier(0);
  compute_kt(1);
  WAITVM(8);  __builtin_amdgcn_s_barrier(); __builtin_amdgcn_sched_barrier(0);
  compute_kt(2);
  WAITVM(0);  __builtin_amdgcn_s_barrier(); __builtin_amdgcn_sched_barrier(0);
  compute_kt(3);

  // Epilogue. C/D layout: col = lane&15, row = (lane>>4)*4 + reg (m89-verified).
  // e^x = exp2f(frac) * 2^k in f64: exponent field stays in (0,2046) -> always finite.
  const int g = lane >> 4;
  const int cl = lane & 15;
  double rs[4][4] = {};

#pragma unroll
  for (int m = 0; m < 4; ++m) {
    const int rowbase = bi * BM + wr * 64 + m * 16 + g * 4;
#pragma unroll
    for (int r2 = 0; r2 < 4; ++r2) {
      const int row = rowbase + r2;
      const float apv = ap[row];
      const unsigned long long mw = pm[(size_t)row * PMW + bj * 2 + wc];  // broadcast
#pragma unroll
      for (int n = 0; n < 4; ++n) {
        const float x = acc[m][n][r2] - apv;
        const float tt = x * 1.44269504088896340736f;
        const float kf = floorf(tt);
        const float mant = exp2f(tt - kf);
        const long long ebits = (long long)(1023 + (int)kf) << 52;
        const double sc = __builtin_bit_cast(double, ebits);
        const bool msk = (mw >> (n * 16 + cl)) & 1;
        rs[m][r2] += msk ? (double)mant * sc : 0.0;
      }
    }
  }
#pragma unroll
  for (int m = 0; m < 4; ++m)
#pragma unroll
    for (int r2 = 0; r2 < 4; ++r2) {
      double v = rs[m][r2];
#pragma unroll
      for (int off = 8; off >= 1; off >>= 1) v += __shfl_xor(v, off, 64);
      if (cl == 0) atomicAdd(&rowsum[bi * BM + wr * 64 + m * 16 + g * 4 + r2], v);
    }
}

// j_i = log1p(rowsum_i) in f64 (finite); mean over rows.
__global__ void finalize_kernel(const double* __restrict__ rowsum, float* __restrict__ out) {
  __shared__ double red[4];
  const int t = threadIdx.x;
  double s = 0.0;
  for (int i = t; i < NR; i += 256) s += log1p(rowsum[i]);
#pragma unroll
  for (int off = 32; off >= 1; off >>= 1) s += __shfl_xor(s, off, 64);
  if ((t & 63) == 0) red[t >> 6] = s;
  __syncthreads();
  if (t == 0) out[0] = (float)((red[0] + red[1] + red[2] + red[3]) * (1.0 / NR));
}

extern "C" void kernel_launch(void* const* d_in, const int* in_sizes, int n_in,
                              void* d_out, int out_size, void* d_ws, size_t ws_size,
                              hipStream_t stream) {
  const float* emb = (const float*)d_in[0];
  // d_in[1] (pos_mask) unused by the reference.
  const unsigned char* negm = (const unsigned char*)d_in[2];
  float* out = (float*)d_out;
  char* ws = (char*)d_ws;
  unsigned short* ebf = (unsigned short*)ws;                        // 4 MB bf16 embeddings
  unsigned long long* pm = (unsigned long long*)(ws + (1u << 22));  // 4 MB packed mask
  float* ap = (float*)(ws + (2u << 22));                            // 16 KB
  double* rowsum = (double*)(ws + (2u << 22) + 16384);              // 32 KB

  cvt_kernel<<<dim3(TWO_N * D / 8 / 256), dim3(256), 0, stream>>>(emb, ebf);
  repack_kernel<<<dim3(NR * PMW / 256), dim3(256), 0, stream>>>(negm, pm);
  ap_zero_kernel<<<dim3(NR / 4), dim3(256), 0, stream>>>(emb, ap, rowsum);
  fused_mfma<<<dim3((NR / BM) * (TWO_N / BN)), dim3(256), 0, stream>>>(ebf, pm, ap, rowsum);
  finalize_kernel<<<dim3(1), dim3(256), 0, stream>>>(rowsum, out);
}

// Round 8
// 273.742 us; speedup vs baseline: 1.2379x; 1.2379x over previous
//
#include <hip/hip_runtime.h>
#include <math.h>

#define TWO_N 8192
#define NR 4096
#define D 256
#define PMW 128  // u64 mask words per row
#define L2E 1.44269504088896340736f

typedef __attribute__((ext_vector_type(8))) short bf16x8;
typedef __attribute__((ext_vector_type(4))) float f32x4;

#define AS1V const __attribute__((address_space(1))) void
#define AS3V __attribute__((address_space(3))) void
#define WAITVM(n) asm volatile("s_waitcnt vmcnt(" #n ")" ::: "memory")

__device__ inline unsigned short f2bf(float x) {
  unsigned u = __builtin_bit_cast(unsigned, x);
  u += 0x7fffu + ((u >> 16) & 1u);  // RNE
  return (unsigned short)(u >> 16);
}

// Fused prep: [0,1024) cvt f32->bf16; [1024,3072) mask byte->bit repack;
// [3072,4096) apl[i] = -dot(e_i, e_{i+NR})*log2e + rowsum zero.
__global__ __launch_bounds__(256) void prep_kernel(
    const float* __restrict__ emb, const unsigned char* __restrict__ negm,
    unsigned short* __restrict__ ebf, unsigned long long* __restrict__ pm,
    float* __restrict__ apl, double* __restrict__ rowsum) {
  const int b = blockIdx.x, t = threadIdx.x;
  if (b < 1024) {
    const size_t i = ((size_t)b * 256 + t) * 8;
    const float4 a = *reinterpret_cast<const float4*>(emb + i);
    const float4 c = *reinterpret_cast<const float4*>(emb + i + 4);
    union { unsigned short s[8]; bf16x8 v; } o;
    o.s[0] = f2bf(a.x); o.s[1] = f2bf(a.y); o.s[2] = f2bf(a.z); o.s[3] = f2bf(a.w);
    o.s[4] = f2bf(c.x); o.s[5] = f2bf(c.y); o.s[6] = f2bf(c.z); o.s[7] = f2bf(c.w);
    *reinterpret_cast<bf16x8*>(ebf + i) = o.v;
  } else if (b < 3072) {
    const int w = (b - 1024) * 256 + t;  // u64 word index
    const uint4* p = reinterpret_cast<const uint4*>(negm + (size_t)w * 64);
    unsigned long long acc = 0;
#pragma unroll
    for (int q = 0; q < 4; ++q) {
      const uint4 v = p[q];
      unsigned bb = 0;
      bb |= (v.x & 1u) | ((v.x >> 7) & 2u) | ((v.x >> 14) & 4u) | ((v.x >> 21) & 8u);
      bb |= ((v.y & 1u) | ((v.y >> 7) & 2u) | ((v.y >> 14) & 4u) | ((v.y >> 21) & 8u)) << 4;
      bb |= ((v.z & 1u) | ((v.z >> 7) & 2u) | ((v.z >> 14) & 4u) | ((v.z >> 21) & 8u)) << 8;
      bb |= ((v.w & 1u) | ((v.w >> 7) & 2u) | ((v.w >> 14) & 4u) | ((v.w >> 21) & 8u)) << 12;
      acc |= (unsigned long long)bb << (q * 16);
    }
    pm[w] = acc;
  } else {
    const int lane = t & 63, wid = t >> 6;
    const int i = (b - 3072) * 4 + wid;
    const float4 a = *reinterpret_cast<const float4*>(emb + (size_t)i * D + lane * 4);
    const float4 c = *reinterpret_cast<const float4*>(emb + (size_t)(i + NR) * D + lane * 4);
    float s = a.x * c.x + a.y * c.y + a.z * c.z + a.w * c.w;
#pragma unroll
    for (int off = 32; off >= 1; off >>= 1) s += __shfl_xor(s, off, 64);
    if (lane == 0) { apl[i] = -s * L2E; rowsum[i] = 0.0; }
  }
}

// One block per CU (grid 256): 128-row panel x 1024 cols (8 bj tiles).
// A whole-K resident (4x16KB); B 4-slot ring, counted vmcnt(4), 2 barriers/tile.
// Row partials in f64 registers across all bj; atomics once at block end.
__global__ __launch_bounds__(512) void fused_mfma(
    const unsigned short* __restrict__ ebf, const unsigned long long* __restrict__ pm,
    const float* __restrict__ apl, double* __restrict__ rowsum) {
  __shared__ unsigned short As[4][128 * 64];
  __shared__ unsigned short Bs[4][128 * 64];
  const int t = threadIdx.x, lane = t & 63, wid = t >> 6;
  const int wr = wid >> 2, wc = wid & 3;  // 2x4 wave grid: 64x32 tile per wave
  // XCD swizzle: 256 blocks, XCD k = bIdx&7 gets 4 consecutive row panels.
  const int sw = (blockIdx.x & 7) * 32 + (blockIdx.x >> 3);
  const int bi = sw >> 3, chunk = sw & 7;
  const int g = lane >> 4, cl = lane & 15;
  const int srow = lane >> 3;
  const int sc8 = ((lane & 7) ^ srow) * 8;  // inverse-swizzled source chunk (round-7-verified)

  // Per-thread row constants (rows fixed for whole block). Issued first (oldest VMEM).
  float apv[4][4];
#pragma unroll
  for (int m = 0; m < 4; ++m)
#pragma unroll
    for (int r2 = 0; r2 < 4; ++r2)
      apv[m][r2] = apl[bi * 128 + wr * 64 + m * 16 + g * 4 + r2];

  // A panel: all 4 K-tiles, 2 instr/wave/tile (8 rows x 8 chunks each).
#pragma unroll
  for (int kt = 0; kt < 4; ++kt)
#pragma unroll
    for (int q = 0; q < 2; ++q) {
      const int rbase = wid * 16 + q * 8;
      const unsigned short* gp = ebf + (size_t)(bi * 128 + rbase + srow) * D + kt * 64 + sc8;
      __builtin_amdgcn_global_load_lds((AS1V*)gp, (AS3V*)(As[kt] + rbase * 64), 16, 0, 0);
    }

  auto STAGEB = [&](int gk) {  // stage B tile gk (slot = gk&3 = its kt)
    const int kt = gk & 3, bjj = gk >> 2;
#pragma unroll
    for (int q = 0; q < 2; ++q) {
      const int rbase = wid * 16 + q * 8;
      const unsigned short* gp =
          ebf + (size_t)(chunk * 1024 + bjj * 128 + rbase + srow) * D + kt * 64 + sc8;
      __builtin_amdgcn_global_load_lds((AS1V*)gp, (AS3V*)(Bs[kt] + rbase * 64), 16, 0, 0);
    }
  };
  STAGEB(0); STAGEB(1); STAGEB(2);

  double rs[4][4] = {};

  for (int bj = 0; bj < 8; ++bj) {
    f32x4 acc[4][2] = {};
#pragma unroll
    for (int kt = 0; kt < 4; ++kt) {
      const int gkt = bj * 4 + kt;
      // Need tile gkt landed; tiles gkt+1,gkt+2 (2 instr each) may stay in flight.
      if (kt == 2 && bj == 7) { WAITVM(2); }
      else if (kt == 3 && bj == 7) { WAITVM(0); }
      else { WAITVM(4); }
      __builtin_amdgcn_s_barrier();
      __builtin_amdgcn_sched_barrier(0);
      __builtin_amdgcn_s_setprio(1);
#pragma unroll
      for (int kk = 0; kk < 2; ++kk) {
        const int cswz = ((kk * 4 + g) ^ (lane & 7)) * 8;
        bf16x8 af[4], bf2[2];
#pragma unroll
        for (int m = 0; m < 4; ++m)
          af[m] = *reinterpret_cast<const bf16x8*>(&As[kt][(wr * 64 + m * 16 + cl) * 64 + cswz]);
#pragma unroll
        for (int n = 0; n < 2; ++n)
          bf2[n] = *reinterpret_cast<const bf16x8*>(&Bs[kt][(wc * 32 + n * 16 + cl) * 64 + cswz]);
#pragma unroll
        for (int m = 0; m < 4; ++m)
#pragma unroll
          for (int n = 0; n < 2; ++n)
            acc[m][n] = __builtin_amdgcn_mfma_f32_16x16x32_bf16(af[m], bf2[n], acc[m][n], 0, 0, 0);
      }
      __builtin_amdgcn_s_setprio(0);
      __builtin_amdgcn_s_barrier();       // ring WAR: all waves done reading before restage
      __builtin_amdgcn_sched_barrier(0);
      if (kt < 3) {
        if (gkt + 3 < 32) STAGEB(gkt + 3);
      }
    }
    // Epilogue for bj. Load mask words FIRST (older than next STAGE -> compiler
    // waits on them won't drain the pipeline), pin order, then stage, then VALU.
    unsigned long long mw[4][4];
#pragma unroll
    for (int m = 0; m < 4; ++m)
#pragma unroll
      for (int r2 = 0; r2 < 4; ++r2) {
        const int row = bi * 128 + wr * 64 + m * 16 + g * 4 + r2;
        mw[m][r2] = pm[(size_t)row * PMW + (chunk * 8 + bj) * 2 + (wc >> 1)];
      }
    __builtin_amdgcn_sched_barrier(0);
    if (bj * 4 + 6 < 32) STAGEB(bj * 4 + 6);  // tile (gkt=bj*4+3)+3
    // e^x = 2^frac * 2^k, accumulated f64 via v_ldexp_f64. Clamp tt so the
    // f64 row sum can never overflow (8192 * 2^961 < DBL_MAX) -> always finite.
#pragma unroll
    for (int m = 0; m < 4; ++m)
#pragma unroll
      for (int r2 = 0; r2 < 4; ++r2) {
#pragma unroll
        for (int n = 0; n < 2; ++n) {
          float tt = fmaf(acc[m][n][r2], L2E, apv[m][r2]);
          tt = fminf(fmaxf(tt, -1020.f), 960.f);
          const float kf = floorf(tt);
          float mant;
          asm("v_exp_f32 %0, %1" : "=v"(mant) : "v"(tt - kf));  // 2^frac, frac in [0,1)
          const int bitp = (wc & 1) * 32 + n * 16 + cl;
          mant = ((mw[m][r2] >> bitp) & 1) ? mant : 0.f;
          rs[m][r2] += ldexp((double)mant, (int)kf);
        }
      }
  }

  // Block-end: reduce over the 16 cl-lanes (offsets <16 stay within g-group),
  // one f64 atomic per row per wave.
#pragma unroll
  for (int m = 0; m < 4; ++m)
#pragma unroll
    for (int r2 = 0; r2 < 4; ++r2) {
      double v = rs[m][r2];
#pragma unroll
      for (int off = 8; off >= 1; off >>= 1) v += __shfl_xor(v, off, 64);
      if (cl == 0)
        atomicAdd(&rowsum[bi * 128 + wr * 64 + m * 16 + g * 4 + r2], v);
    }
}

// j_i = log1p(rowsum_i) in f64 (finite by construction); mean over rows.
__global__ __launch_bounds__(1024) void finalize_kernel(const double* __restrict__ rowsum,
                                                        float* __restrict__ out) {
  __shared__ double red[16];
  const int t = threadIdx.x;
  double s = 0.0;
#pragma unroll
  for (int k = 0; k < 4; ++k) s += log1p(rowsum[t + k * 1024]);
#pragma unroll
  for (int off = 32; off >= 1; off >>= 1) s += __shfl_xor(s, off, 64);
  if ((t & 63) == 0) red[t >> 6] = s;
  __syncthreads();
  if (t == 0) {
    double tot = 0.0;
#pragma unroll
    for (int w = 0; w < 16; ++w) tot += red[w];
    out[0] = (float)(tot * (1.0 / NR));
  }
}

extern "C" void kernel_launch(void* const* d_in, const int* in_sizes, int n_in,
                              void* d_out, int out_size, void* d_ws, size_t ws_size,
                              hipStream_t stream) {
  const float* emb = (const float*)d_in[0];
  // d_in[1] (pos_mask) unused by the reference.
  const unsigned char* negm = (const unsigned char*)d_in[2];
  float* out = (float*)d_out;
  char* ws = (char*)d_ws;
  unsigned short* ebf = (unsigned short*)ws;                        // 4 MB bf16 embeddings
  unsigned long long* pm = (unsigned long long*)(ws + (1u << 22));  // 4 MB packed mask
  float* apl = (float*)(ws + (2u << 22));                           // 16 KB (-ap*log2e)
  double* rowsum = (double*)(ws + (2u << 22) + 16384);              // 32 KB

  prep_kernel<<<dim3(4096), dim3(256), 0, stream>>>(emb, negm, ebf, pm, apl, rowsum);
  fused_mfma<<<dim3(256), dim3(512), 0, stream>>>(ebf, pm, apl, rowsum);
  finalize_kernel<<<dim3(1), dim3(1024), 0, stream>>>(rowsum, out);
}

// Round 9
// 267.313 us; speedup vs baseline: 1.2677x; 1.0241x over previous
//
#include <hip/hip_runtime.h>
#include <math.h>

#define TWO_N 8192
#define NR 4096
#define D 256
#define PMW 128  // u64 mask words per row
#define L2E 1.44269504088896340736f

typedef __attribute__((ext_vector_type(8))) short bf16x8;
typedef __attribute__((ext_vector_type(4))) float f32x4;

#define AS1V const __attribute__((address_space(1))) void
#define AS3V __attribute__((address_space(3))) void
#define WAITVM(n) asm volatile("s_waitcnt vmcnt(" #n ")" ::: "memory")

__device__ inline unsigned short f2bf(float x) {
  unsigned u = __builtin_bit_cast(unsigned, x);
  u += 0x7fffu + ((u >> 16) & 1u);  // RNE
  return (unsigned short)(u >> 16);
}

__device__ inline float exp2_hw(float x) {
#if __has_builtin(__builtin_amdgcn_exp2f)
  return __builtin_amdgcn_exp2f(x);
#else
  float r;
  asm("v_exp_f32 %0, %1" : "=v"(r) : "v"(x));
  return r;
#endif
}

// Fused prep: [0,1024) cvt f32->bf16; [1024,3072) mask byte->bit repack;
// [3072,4096) apl[i] = -dot(e_i, e_{i+NR})*log2e + rowsum zero.
__global__ __launch_bounds__(256) void prep_kernel(
    const float* __restrict__ emb, const unsigned char* __restrict__ negm,
    unsigned short* __restrict__ ebf, unsigned long long* __restrict__ pm,
    float* __restrict__ apl, double* __restrict__ rowsum) {
  const int b = blockIdx.x, t = threadIdx.x;
  if (b < 1024) {
    const size_t i = ((size_t)b * 256 + t) * 8;
    const float4 a = *reinterpret_cast<const float4*>(emb + i);
    const float4 c = *reinterpret_cast<const float4*>(emb + i + 4);
    union { unsigned short s[8]; bf16x8 v; } o;
    o.s[0] = f2bf(a.x); o.s[1] = f2bf(a.y); o.s[2] = f2bf(a.z); o.s[3] = f2bf(a.w);
    o.s[4] = f2bf(c.x); o.s[5] = f2bf(c.y); o.s[6] = f2bf(c.z); o.s[7] = f2bf(c.w);
    *reinterpret_cast<bf16x8*>(ebf + i) = o.v;
  } else if (b < 3072) {
    const int w = (b - 1024) * 256 + t;  // u64 word index
    const uint4* p = reinterpret_cast<const uint4*>(negm + (size_t)w * 64);
    unsigned long long acc = 0;
#pragma unroll
    for (int q = 0; q < 4; ++q) {
      const uint4 v = p[q];
      unsigned bb = 0;
      bb |= (v.x & 1u) | ((v.x >> 7) & 2u) | ((v.x >> 14) & 4u) | ((v.x >> 21) & 8u);
      bb |= ((v.y & 1u) | ((v.y >> 7) & 2u) | ((v.y >> 14) & 4u) | ((v.y >> 21) & 8u)) << 4;
      bb |= ((v.z & 1u) | ((v.z >> 7) & 2u) | ((v.z >> 14) & 4u) | ((v.z >> 21) & 8u)) << 8;
      bb |= ((v.w & 1u) | ((v.w >> 7) & 2u) | ((v.w >> 14) & 4u) | ((v.w >> 21) & 8u)) << 12;
      acc |= (unsigned long long)bb << (q * 16);
    }
    pm[w] = acc;
  } else {
    const int lane = t & 63, wid = t >> 6;
    const int i = (b - 3072) * 4 + wid;
    const float4 a = *reinterpret_cast<const float4*>(emb + (size_t)i * D + lane * 4);
    const float4 c = *reinterpret_cast<const float4*>(emb + (size_t)(i + NR) * D + lane * 4);
    float s = a.x * c.x + a.y * c.y + a.z * c.z + a.w * c.w;
#pragma unroll
    for (int off = 32; off >= 1; off >>= 1) s += __shfl_xor(s, off, 64);
    if (lane == 0) { apl[i] = -s * L2E; rowsum[i] = 0.0; }
  }
}

// One block per CU (grid 256, 512 thr): 128-row panel x 1024 cols (4 bj of 256).
// A whole-K resident (64 KB); B 2-slot ring (2x32 KB); waves 2x4, tile 64x64.
// Counted vmcnt(4): tile gkt+1 always in flight during compute of gkt.
__global__ __launch_bounds__(512) void fused_mfma(
    const unsigned short* __restrict__ ebf, const unsigned long long* __restrict__ pm,
    const float* __restrict__ apl, double* __restrict__ rowsum) {
  __shared__ unsigned short As[4][128 * 64];  // 64 KB
  __shared__ unsigned short Bs[2][256 * 64];  // 64 KB
  const int t = threadIdx.x, lane = t & 63, wid = t >> 6;
  const int wr = wid >> 2, wc = wid & 3;  // 2x4 wave grid, 64x64 per wave
  const int sw = (blockIdx.x & 7) * 32 + (blockIdx.x >> 3);  // XCD swizzle (256 = 8*32)
  const int bi = sw >> 3, chunk = sw & 7;
  const int g = lane >> 4, cl = lane & 15;
  const int srow = lane >> 3;
  const int sc8 = ((lane & 7) ^ srow) * 8;  // inverse-swizzled source chunk (r7-verified)

  // Row constants (oldest VMEM, retired before first WAITVM target).
  float apv[4][4];
#pragma unroll
  for (int m = 0; m < 4; ++m) {
    const float4 v = *reinterpret_cast<const float4*>(apl + bi * 128 + wr * 64 + m * 16 + g * 4);
    apv[m][0] = v.x; apv[m][1] = v.y; apv[m][2] = v.z; apv[m][3] = v.w;
  }

  // A panel: 4 kt slots x 2 instr/wave (8 rows each).
#pragma unroll
  for (int kt = 0; kt < 4; ++kt)
#pragma unroll
    for (int q = 0; q < 2; ++q) {
      const int rbase = wid * 16 + q * 8;
      const unsigned short* gp = ebf + (size_t)(bi * 128 + rbase + srow) * D + kt * 64 + sc8;
      __builtin_amdgcn_global_load_lds((AS1V*)gp, (AS3V*)(As[kt] + rbase * 64), 16, 0, 0);
    }

  auto STAGEB = [&](int gk) {  // B tile gk (bj = gk>>2, kt = gk&3) -> slot gk&1; 4 instr/wave
    const int kt = gk & 3, bjj = gk >> 2;
#pragma unroll
    for (int q = 0; q < 4; ++q) {
      const int rbase = wid * 32 + q * 8;
      const unsigned short* gp =
          ebf + (size_t)(chunk * 1024 + bjj * 256 + rbase + srow) * D + kt * 64 + sc8;
      __builtin_amdgcn_global_load_lds((AS1V*)gp, (AS3V*)(Bs[gk & 1] + rbase * 64), 16, 0, 0);
    }
  };
  STAGEB(0); STAGEB(1);

  double rs[4][4] = {};

  for (int bj = 0; bj < 4; ++bj) {
    f32x4 acc[4][4] = {};
    unsigned long long mw[4][4];
#pragma unroll
    for (int kt = 0; kt < 4; ++kt) {
      const int gkt = bj * 4 + kt;
      // Tile gkt must be landed; tile gkt+1 (4 instr, newest) may stay in flight.
      if (kt == 3) { if (bj == 3) { WAITVM(0); } else { WAITVM(4); } }
      else { WAITVM(4); }
      __builtin_amdgcn_s_barrier();
      __builtin_amdgcn_sched_barrier(0);
      __builtin_amdgcn_s_setprio(1);
#pragma unroll
      for (int kk = 0; kk < 2; ++kk) {
        const int cswz = ((kk * 4 + g) ^ (lane & 7)) * 8;
        bf16x8 af[4], bf[4];
#pragma unroll
        for (int m = 0; m < 4; ++m)
          af[m] = *reinterpret_cast<const bf16x8*>(&As[kt][(wr * 64 + m * 16 + cl) * 64 + cswz]);
#pragma unroll
        for (int n = 0; n < 4; ++n)
          bf[n] = *reinterpret_cast<const bf16x8*>(&Bs[gkt & 1][(wc * 64 + n * 16 + cl) * 64 + cswz]);
#pragma unroll
        for (int m = 0; m < 4; ++m)
#pragma unroll
          for (int n = 0; n < 4; ++n)
            acc[m][n] = __builtin_amdgcn_mfma_f32_16x16x32_bf16(af[m], bf[n], acc[m][n], 0, 0, 0);
      }
      __builtin_amdgcn_s_setprio(0);
      __builtin_amdgcn_s_barrier();  // ring WAR: all waves done with slot gkt&1
      __builtin_amdgcn_sched_barrier(0);
      if (kt == 3) {  // pm loads BEFORE the stage: newest-4 invariant holds
#pragma unroll
        for (int m = 0; m < 4; ++m)
#pragma unroll
          for (int r2 = 0; r2 < 4; ++r2) {
            const int row = bi * 128 + wr * 64 + m * 16 + g * 4 + r2;
            mw[m][r2] = pm[(size_t)row * PMW + chunk * 16 + bj * 4 + wc];
          }
        __builtin_amdgcn_sched_barrier(0);
      }
      if (gkt + 2 < 16) STAGEB(gkt + 2);  // writes slot gkt&1, safe after barrier
      __builtin_amdgcn_sched_barrier(0);
    }
    // Epilogue for bj: e^x = 2^frac * 2^k, k via integer exponent-bit build
    // (no libcall), f64 fma accumulate. Clamp keeps 1023+k in (0,2046) -> finite.
#pragma unroll
    for (int m = 0; m < 4; ++m)
#pragma unroll
      for (int n = 0; n < 4; ++n)
#pragma unroll
        for (int r2 = 0; r2 < 4; ++r2) {
          float tt = fmaf(acc[m][n][r2], L2E, apv[m][r2]);
          tt = fminf(fmaxf(tt, -1020.f), 1000.f);
          const float kf = floorf(tt);
          const float mant = exp2_hw(tt - kf);
          const float mm = ((mw[m][r2] >> (n * 16 + cl)) & 1) ? mant : 0.f;
          const long long ebits = (long long)(1023 + (int)kf) << 52;
          rs[m][r2] += (double)mm * __builtin_bit_cast(double, ebits);
        }
  }

  // Reduce over the 16 col-lanes sharing each row; one f64 atomic per row per wave.
#pragma unroll
  for (int m = 0; m < 4; ++m)
#pragma unroll
    for (int r2 = 0; r2 < 4; ++r2) {
      double v = rs[m][r2];
#pragma unroll
      for (int off = 8; off >= 1; off >>= 1) v += __shfl_xor(v, off, 64);
      if (cl == 0) atomicAdd(&rowsum[bi * 128 + wr * 64 + m * 16 + g * 4 + r2], v);
    }
}

// j_i = log1p(rowsum_i) in f64 (finite by construction); mean over rows.
__global__ __launch_bounds__(1024) void finalize_kernel(const double* __restrict__ rowsum,
                                                        float* __restrict__ out) {
  __shared__ double red[16];
  const int t = threadIdx.x;
  double s = 0.0;
#pragma unroll
  for (int k = 0; k < 4; ++k) s += log1p(rowsum[t + k * 1024]);
#pragma unroll
  for (int off = 32; off >= 1; off >>= 1) s += __shfl_xor(s, off, 64);
  if ((t & 63) == 0) red[t >> 6] = s;
  __syncthreads();
  if (t == 0) {
    double tot = 0.0;
#pragma unroll
    for (int w = 0; w < 16; ++w) tot += red[w];
    out[0] = (float)(tot * (1.0 / NR));
  }
}

extern "C" void kernel_launch(void* const* d_in, const int* in_sizes, int n_in,
                              void* d_out, int out_size, void* d_ws, size_t ws_size,
                              hipStream_t stream) {
  const float* emb = (const float*)d_in[0];
  // d_in[1] (pos_mask) unused by the reference.
  const unsigned char* negm = (const unsigned char*)d_in[2];
  float* out = (float*)d_out;
  char* ws = (char*)d_ws;
  unsigned short* ebf = (unsigned short*)ws;                        // 4 MB bf16 embeddings
  unsigned long long* pm = (unsigned long long*)(ws + (1u << 22));  // 4 MB packed mask
  float* apl = (float*)(ws + (2u << 22));                           // 16 KB (-ap*log2e)
  double* rowsum = (double*)(ws + (2u << 22) + 16384);              // 32 KB

  prep_kernel<<<dim3(4096), dim3(256), 0, stream>>>(emb, negm, ebf, pm, apl, rowsum);
  fused_mfma<<<dim3(256), dim3(512), 0, stream>>>(ebf, pm, apl, rowsum);
  finalize_kernel<<<dim3(1), dim3(1024), 0, stream>>>(rowsum, out);
}

// Round 10
// 265.438 us; speedup vs baseline: 1.2766x; 1.0071x over previous
//
#include <hip/hip_runtime.h>
#include <math.h>

#define TWO_N 8192
#define NR 4096
#define D 256
#define PMW 128  // u64 mask words per row
#define L2E 1.44269504088896340736f

typedef __attribute__((ext_vector_type(8))) short bf16x8;
typedef __attribute__((ext_vector_type(4))) float f32x4;

#define AS1V const __attribute__((address_space(1))) void
#define AS3V __attribute__((address_space(3))) void
#define WAITVM(n) asm volatile("s_waitcnt vmcnt(" #n ")" ::: "memory")

__device__ inline unsigned short f2bf(float x) {
  unsigned u = __builtin_bit_cast(unsigned, x);
  u += 0x7fffu + ((u >> 16) & 1u);  // RNE
  return (unsigned short)(u >> 16);
}

__device__ inline float exp2_hw(float x) {
  float r;
  asm("v_exp_f32 %0, %1" : "=v"(r) : "v"(x));
  return r;
}

// Fused prep: [0,1024) cvt f32->bf16; [1024,3072) mask byte->bit repack;
// [3072,4096) apl[i] = -dot(e_i, e_{i+NR})*log2e + rowsum zero.
__global__ __launch_bounds__(256) void prep_kernel(
    const float* __restrict__ emb, const unsigned char* __restrict__ negm,
    unsigned short* __restrict__ ebf, unsigned long long* __restrict__ pm,
    float* __restrict__ apl, double* __restrict__ rowsum) {
  const int b = blockIdx.x, t = threadIdx.x;
  if (b < 1024) {
    const size_t i = ((size_t)b * 256 + t) * 8;
    const float4 a = *reinterpret_cast<const float4*>(emb + i);
    const float4 c = *reinterpret_cast<const float4*>(emb + i + 4);
    union { unsigned short s[8]; bf16x8 v; } o;
    o.s[0] = f2bf(a.x); o.s[1] = f2bf(a.y); o.s[2] = f2bf(a.z); o.s[3] = f2bf(a.w);
    o.s[4] = f2bf(c.x); o.s[5] = f2bf(c.y); o.s[6] = f2bf(c.z); o.s[7] = f2bf(c.w);
    *reinterpret_cast<bf16x8*>(ebf + i) = o.v;
  } else if (b < 3072) {
    const int w = (b - 1024) * 256 + t;  // u64 word index
    const uint4* p = reinterpret_cast<const uint4*>(negm + (size_t)w * 64);
    unsigned long long acc = 0;
#pragma unroll
    for (int q = 0; q < 4; ++q) {
      const uint4 v = p[q];
      unsigned bb = 0;
      bb |= (v.x & 1u) | ((v.x >> 7) & 2u) | ((v.x >> 14) & 4u) | ((v.x >> 21) & 8u);
      bb |= ((v.y & 1u) | ((v.y >> 7) & 2u) | ((v.y >> 14) & 4u) | ((v.y >> 21) & 8u)) << 4;
      bb |= ((v.z & 1u) | ((v.z >> 7) & 2u) | ((v.z >> 14) & 4u) | ((v.z >> 21) & 8u)) << 8;
      bb |= ((v.w & 1u) | ((v.w >> 7) & 2u) | ((v.w >> 14) & 4u) | ((v.w >> 21) & 8u)) << 12;
      acc |= (unsigned long long)bb << (q * 16);
    }
    pm[w] = acc;
  } else {
    const int lane = t & 63, wid = t >> 6;
    const int i = (b - 3072) * 4 + wid;
    const float4 a = *reinterpret_cast<const float4*>(emb + (size_t)i * D + lane * 4);
    const float4 c = *reinterpret_cast<const float4*>(emb + (size_t)(i + NR) * D + lane * 4);
    float s = a.x * c.x + a.y * c.y + a.z * c.z + a.w * c.w;
#pragma unroll
    for (int off = 32; off >= 1; off >>= 1) s += __shfl_xor(s, off, 64);
    if (lane == 0) { apl[i] = -s * L2E; rowsum[i] = 0.0; }
  }
}

// One block per CU (grid 256, 512 thr): 128-row panel x 1024 cols (4 bj of 256).
// A whole-K resident (64 KB); B 2-slot ring (2x32 KB); waves 2x4, tile 64x64.
// Counted vmcnt(4): tile gkt+1 always in flight during compute of gkt.
// Block->work mapping: chunk = blockIdx&7 == XCD id (round-robin dispatch), so
// all 32 blocks on an XCD share ONE 512 KB B-chunk in its L2 (x32 reuse);
// unique bytes/XCD = B 0.5 + A 2.0 + pm 0.5 = 3 MB < 4 MB L2.
__global__ __launch_bounds__(512) void fused_mfma(
    const unsigned short* __restrict__ ebf, const unsigned long long* __restrict__ pm,
    const float* __restrict__ apl, double* __restrict__ rowsum) {
  __shared__ unsigned short As[4][128 * 64];  // 64 KB
  __shared__ unsigned short Bs[2][256 * 64];  // 64 KB
  const int t = threadIdx.x, lane = t & 63, wid = t >> 6;
  const int wr = wid >> 2, wc = wid & 3;  // 2x4 wave grid, 64x64 per wave
  const int bi = blockIdx.x >> 3;   // 0..31 row panel (varies within XCD)
  const int chunk = blockIdx.x & 7; // 0..7 B-chunk == XCD id (L2-resident)
  const int g = lane >> 4, cl = lane & 15;
  const int srow = lane >> 3;
  const int sc8 = ((lane & 7) ^ srow) * 8;  // inverse-swizzled source chunk (r7-verified)

  // Row constants (oldest VMEM, retired before first WAITVM target).
  float apv[4][4];
#pragma unroll
  for (int m = 0; m < 4; ++m) {
    const float4 v = *reinterpret_cast<const float4*>(apl + bi * 128 + wr * 64 + m * 16 + g * 4);
    apv[m][0] = v.x; apv[m][1] = v.y; apv[m][2] = v.z; apv[m][3] = v.w;
  }

  // A panel: 4 kt slots x 2 instr/wave (8 rows each).
#pragma unroll
  for (int kt = 0; kt < 4; ++kt)
#pragma unroll
    for (int q = 0; q < 2; ++q) {
      const int rbase = wid * 16 + q * 8;
      const unsigned short* gp = ebf + (size_t)(bi * 128 + rbase + srow) * D + kt * 64 + sc8;
      __builtin_amdgcn_global_load_lds((AS1V*)gp, (AS3V*)(As[kt] + rbase * 64), 16, 0, 0);
    }

  auto STAGEB = [&](int gk) {  // B tile gk (bj = gk>>2, kt = gk&3) -> slot gk&1; 4 instr/wave
    const int kt = gk & 3, bjj = gk >> 2;
#pragma unroll
    for (int q = 0; q < 4; ++q) {
      const int rbase = wid * 32 + q * 8;
      const unsigned short* gp =
          ebf + (size_t)(chunk * 1024 + bjj * 256 + rbase + srow) * D + kt * 64 + sc8;
      __builtin_amdgcn_global_load_lds((AS1V*)gp, (AS3V*)(Bs[gk & 1] + rbase * 64), 16, 0, 0);
    }
  };
  STAGEB(0); STAGEB(1);

  double rs[4][4] = {};

  for (int bj = 0; bj < 4; ++bj) {
    f32x4 acc[4][4] = {};
    unsigned long long mw[4][4];
#pragma unroll
    for (int kt = 0; kt < 4; ++kt) {
      const int gkt = bj * 4 + kt;
      // Tile gkt must be landed; tile gkt+1 (4 instr, newest) may stay in flight.
      if (kt == 3) { if (bj == 3) { WAITVM(0); } else { WAITVM(4); } }
      else { WAITVM(4); }
      __builtin_amdgcn_s_barrier();
      __builtin_amdgcn_sched_barrier(0);
      __builtin_amdgcn_s_setprio(1);
#pragma unroll
      for (int kk = 0; kk < 2; ++kk) {
        const int cswz = ((kk * 4 + g) ^ (lane & 7)) * 8;
        bf16x8 af[4], bf[4];
#pragma unroll
        for (int m = 0; m < 4; ++m)
          af[m] = *reinterpret_cast<const bf16x8*>(&As[kt][(wr * 64 + m * 16 + cl) * 64 + cswz]);
#pragma unroll
        for (int n = 0; n < 4; ++n)
          bf[n] = *reinterpret_cast<const bf16x8*>(&Bs[gkt & 1][(wc * 64 + n * 16 + cl) * 64 + cswz]);
#pragma unroll
        for (int m = 0; m < 4; ++m)
#pragma unroll
          for (int n = 0; n < 4; ++n)
            acc[m][n] = __builtin_amdgcn_mfma_f32_16x16x32_bf16(af[m], bf[n], acc[m][n], 0, 0, 0);
      }
      __builtin_amdgcn_s_setprio(0);
      __builtin_amdgcn_s_barrier();  // ring WAR: all waves done with slot gkt&1
      __builtin_amdgcn_sched_barrier(0);
      if (kt == 3) {  // pm loads BEFORE the stage: newest-4 invariant holds
#pragma unroll
        for (int m = 0; m < 4; ++m)
#pragma unroll
          for (int r2 = 0; r2 < 4; ++r2) {
            const int row = bi * 128 + wr * 64 + m * 16 + g * 4 + r2;
            mw[m][r2] = pm[(size_t)row * PMW + chunk * 16 + bj * 4 + wc];
          }
        __builtin_amdgcn_sched_barrier(0);
      }
      if (gkt + 2 < 16) STAGEB(gkt + 2);  // writes slot gkt&1, safe after barrier
      __builtin_amdgcn_sched_barrier(0);
    }
    // Epilogue for bj: e^x = 2^frac * 2^k, k via integer exponent-bit build
    // (no libcall), f64 fma accumulate. Clamp keeps 1023+k in (0,2046) -> finite.
#pragma unroll
    for (int m = 0; m < 4; ++m)
#pragma unroll
      for (int n = 0; n < 4; ++n)
#pragma unroll
        for (int r2 = 0; r2 < 4; ++r2) {
          float tt = fmaf(acc[m][n][r2], L2E, apv[m][r2]);
          tt = fminf(fmaxf(tt, -1020.f), 1000.f);
          const float kf = floorf(tt);
          const float mant = exp2_hw(tt - kf);
          const float mm = ((mw[m][r2] >> (n * 16 + cl)) & 1) ? mant : 0.f;
          const long long ebits = (long long)(1023 + (int)kf) << 52;
          rs[m][r2] += (double)mm * __builtin_bit_cast(double, ebits);
        }
  }

  // Reduce over the 16 col-lanes sharing each row; one f64 atomic per row per wave.
#pragma unroll
  for (int m = 0; m < 4; ++m)
#pragma unroll
    for (int r2 = 0; r2 < 4; ++r2) {
      double v = rs[m][r2];
#pragma unroll
      for (int off = 8; off >= 1; off >>= 1) v += __shfl_xor(v, off, 64);
      if (cl == 0) atomicAdd(&rowsum[bi * 128 + wr * 64 + m * 16 + g * 4 + r2], v);
    }
}

// j_i = log1p(rowsum_i) in f64 (finite by construction); mean over rows.
__global__ __launch_bounds__(1024) void finalize_kernel(const double* __restrict__ rowsum,
                                                        float* __restrict__ out) {
  __shared__ double red[16];
  const int t = threadIdx.x;
  double s = 0.0;
#pragma unroll
  for (int k = 0; k < 4; ++k) s += log1p(rowsum[t + k * 1024]);
#pragma unroll
  for (int off = 32; off >= 1; off >>= 1) s += __shfl_xor(s, off, 64);
  if ((t & 63) == 0) red[t >> 6] = s;
  __syncthreads();
  if (t == 0) {
    double tot = 0.0;
#pragma unroll
    for (int w = 0; w < 16; ++w) tot += red[w];
    out[0] = (float)(tot * (1.0 / NR));
  }
}

extern "C" void kernel_launch(void* const* d_in, const int* in_sizes, int n_in,
                              void* d_out, int out_size, void* d_ws, size_t ws_size,
                              hipStream_t stream) {
  const float* emb = (const float*)d_in[0];
  // d_in[1] (pos_mask) unused by the reference.
  const unsigned char* negm = (const unsigned char*)d_in[2];
  float* out = (float*)d_out;
  char* ws = (char*)d_ws;
  unsigned short* ebf = (unsigned short*)ws;                        // 4 MB bf16 embeddings
  unsigned long long* pm = (unsigned long long*)(ws + (1u << 22));  // 4 MB packed mask
  float* apl = (float*)(ws + (2u << 22));                           // 16 KB (-ap*log2e)
  double* rowsum = (double*)(ws + (2u << 22) + 16384);              // 32 KB

  prep_kernel<<<dim3(4096), dim3(256), 0, stream>>>(emb, negm, ebf, pm, apl, rowsum);
  fused_mfma<<<dim3(256), dim3(512), 0, stream>>>(ebf, pm, apl, rowsum);
  finalize_kernel<<<dim3(1), dim3(1024), 0, stream>>>(rowsum, out);
}